// Round 20
// baseline (52.276 us; speedup 1.0000x reference)
//
#include <hip/hip_runtime.h>

// Problem constants (fixed by the reference)
#define BB 4
#define NN 50000
#define GG 2
#define EE 500000
#define HH 64
#define RR 16

#define CVT (GG * NN)                    // fp8 u-table rows
#define K1B 256                          // K1 blocks total (2 graphs x 128)
#define ROWS_PB ((CVT + K1B - 1) / K1B)  // 391 table rows per K1 block

// Binning geometry (r18 proven config)
#define NTT   512                        // nodes per dst-tile
#define TILES 98                         // ceil(NN / NTT)
#define PBLK  128                        // K1 blocks per graph
#define EPB   ((EE + PBLK - 1) / PBLK)   // 3907 edges per K1 block
#define CAP   64                         // records per (block,tile); mean 40, +3.8 sigma

typedef float f32x2 __attribute__((ext_vector_type(2)));

// ---------------------------------------------------------------------------
// fp8 helpers (OCP e4m3, hw convert on gfx950)
// ---------------------------------------------------------------------------
__device__ inline unsigned int pack4_fp8(float f0, float f1, float f2, float f3) {
    int w = 0;
    w = __builtin_amdgcn_cvt_pk_fp8_f32(f0, f1, w, false);  // bytes 0,1
    w = __builtin_amdgcn_cvt_pk_fp8_f32(f2, f3, w, true);   // bytes 2,3
    return (unsigned int)w;
}

// ---------------------------------------------------------------------------
// K1: u-table fp8 conversion (mask folded into LSBs of bytes 0..3) + edge
// binning. Records {src | dst<<16, ewgt_f32} are STAGED IN LDS per dst-tile,
// then flushed bin-contiguous (coalesced ~512B bursts) at block end — no
// scattered global stores on the hot path. Spill region (rare) keeps
// exactness. Block 0 zeroes `out`.
// ---------------------------------------------------------------------------
__global__ __launch_bounds__(256) void prep_bin_kernel(
    const float* __restrict__ pert_mask, const float* __restrict__ gu,
    const int* __restrict__ esrc, const int* __restrict__ edst,
    const float* __restrict__ ewgt,
    uint4* __restrict__ guh, unsigned long long* __restrict__ bins,
    int* __restrict__ counts, unsigned long long* __restrict__ spill,
    int* __restrict__ scnt, float* __restrict__ out)
{
    int g   = blockIdx.x & 1;
    int blk = blockIdx.x >> 1;
    int tid = threadIdx.x;
    __shared__ unsigned long long lbuf[TILES][CAP];   // 50 KB record stage
    __shared__ int lcnt[TILES];
    __shared__ int lspill;
    if (tid < TILES) lcnt[tid] = 0;
    if (tid == 0) lspill = 0;
    if (blockIdx.x == 0 && tid < BB * HH) out[tid] = 0.f;
    __syncthreads();

    // --- u-table conversion slice (independent of edge slice) ---
    int r0 = blockIdx.x * ROWS_PB;
    int r1 = min(r0 + ROWS_PB, CVT);
    for (int r = r0 + tid; r < r1; r += 256) {
        int n = (r >= NN) ? (r - NN) : r;
        const float4* us = (const float4*)(gu + (size_t)r * RR);
        float4 a0 = us[0], a1 = us[1], a2 = us[2], a3 = us[3];
        uint4 ur;
        ur.x = pack4_fp8(a0.x, a0.y, a0.z, a0.w);
        ur.y = pack4_fp8(a1.x, a1.y, a1.z, a1.w);
        ur.z = pack4_fp8(a2.x, a2.y, a2.z, a2.w);
        ur.w = pack4_fp8(a3.x, a3.y, a3.z, a3.w);
        unsigned int mbits =
            ((pert_mask[0*NN + n] != 0.f) ? 0x1u        : 0u) |
            ((pert_mask[1*NN + n] != 0.f) ? 0x100u      : 0u) |
            ((pert_mask[2*NN + n] != 0.f) ? 0x10000u    : 0u) |
            ((pert_mask[3*NN + n] != 0.f) ? 0x1000000u  : 0u);
        ur.x = (ur.x & 0xFEFEFEFEu) | mbits;
        guh[r] = ur;
    }

    // --- edge binning into LDS stage ---
    int base   = blk * EPB;
    int nE     = min(EPB, EE - base);
    size_t gb  = (size_t)g * EE + base;
    for (int it = tid; it < nE; it += 256) {
        int   s  = __builtin_nontemporal_load(esrc + gb + it);
        int   d  = __builtin_nontemporal_load(edst + gb + it);
        float w0 = __builtin_nontemporal_load(ewgt + gb + it);
        unsigned long long rec =
            (unsigned long long)((unsigned)s | ((unsigned)d << 16)) |
            ((unsigned long long)__float_as_uint(w0) << 32);
        int tt  = d >> 9;               // dst tile
        int pos = atomicAdd(&lcnt[tt], 1);
        if (pos < CAP) {
            lbuf[tt][pos] = rec;
        } else {
            int sp = atomicAdd(&lspill, 1);     // sp < nE <= EPB always
            spill[((size_t)g * PBLK + blk) * EPB + sp] = rec;
        }
    }
    __syncthreads();

    // --- coalesced flush: each wave owns tiles tt = wv, wv+4, ... ---
    int wv = tid >> 6, ln = tid & 63;
    for (int tt = wv; tt < TILES; tt += 4) {
        int cnt = min(lcnt[tt], CAP);
        unsigned long long* dst =
            bins + (((size_t)g * TILES + tt) * PBLK + blk) * CAP;
        for (int i = ln; i < cnt; i += 64)
            dst[i] = lbuf[tt][i];
    }
    if (tid < TILES)
        counts[((size_t)g * TILES + tid) * PBLK + blk] = min(lcnt[tid], CAP);
    if (tid == 0) scnt[g * PBLK + blk] = lspill;
}

// ---------------------------------------------------------------------------
// K2 (bit-identical to r18): per (tile,g) block. v-tile coalesced into padded
// LDS [NTT][17]. Replay records: u-gather (L2) + LDS-v dot + sigmoid,
// accumulate planes, then fused ReLU-mean + out atomics.
// ---------------------------------------------------------------------------
#define P2T 1024

__device__ inline void replay_rec(
    unsigned long long rec, int n0, int ncnt, int g,
    const uint4* __restrict__ guh, float (*vt)[RR + 1], float (*ls)[NTT],
    bool check_range)
{
    unsigned int key = (unsigned int)rec;
    int d = (int)(key >> 16);
    int dl = d - n0;
    if (check_range && ((unsigned)dl >= (unsigned)ncnt)) return;
    int s = key & 0xFFFFu;
    float w0 = __uint_as_float((unsigned int)(rec >> 32));
    uint4 u = guh[(size_t)g * NN + s];      // 16B gather, L2-resident
    const unsigned int* pu = &u.x;
    float dot = 0.f;
#pragma unroll
    for (int q = 0; q < 4; ++q) {
        f32x2 lo = __builtin_amdgcn_cvt_pk_f32_fp8((int)pu[q], false);
        f32x2 hi = __builtin_amdgcn_cvt_pk_f32_fp8((int)pu[q], true);
        dot = fmaf(lo.x, vt[dl][q * 4 + 0], dot);
        dot = fmaf(lo.y, vt[dl][q * 4 + 1], dot);
        dot = fmaf(hi.x, vt[dl][q * 4 + 2], dot);
        dot = fmaf(hi.y, vt[dl][q * 4 + 3], dot);
    }
    float w = w0 / (1.f + __expf(-dot));
    unsigned int mb = (u.x & 1u) | ((u.x >> 7) & 2u) |
                      ((u.x >> 14) & 4u) | ((u.x >> 21) & 8u);
    atomicAdd(&ls[0][dl], w);
    if (mb & 1u) atomicAdd(&ls[1][dl], w);
    if (mb & 2u) atomicAdd(&ls[2][dl], w);
    if (mb & 4u) atomicAdd(&ls[3][dl], w);
    if (mb & 8u) atomicAdd(&ls[4][dl], w);
}

__global__ __launch_bounds__(P2T) void tile_node_kernel(
    const uint4* __restrict__ guh, const unsigned long long* __restrict__ bins,
    const int* __restrict__ counts, const unsigned long long* __restrict__ spill,
    const int* __restrict__ scnt, const float* __restrict__ gv,
    const float* __restrict__ ctx, const float* __restrict__ lin_w,
    const float* __restrict__ lin_b, const float* __restrict__ post_w,
    const float* __restrict__ post_b, const float* __restrict__ mix_w,
    const float* __restrict__ mix_b, float* __restrict__ out)
{
    int t = blockIdx.x;      // tile
    int g = blockIdx.y;      // graph
    int n0 = t * NTT;
    int ncnt = min(NTT, NN - n0);
    __shared__ float vt[NTT][RR + 1];    // 34.8 KB, padded rows
    __shared__ float ls[5][NTT];         // 10 KB
    __shared__ int   lcnts[PBLK];        // 512 B
    __shared__ float red[4][BB * HH];    // 4 KB
    __shared__ float lpw[HH], lpb[HH], lwt[BB];
    int tid = threadIdx.x;

    // v-tile: coalesced float4 reads, scalar LDS stores into padded rows
    for (int i = tid; i < ncnt * 4; i += P2T) {
        int row = i >> 2, q = i & 3;
        float4 v = ((const float4*)(gv + ((size_t)g * NN + n0 + row) * RR))[q];
        vt[row][q * 4 + 0] = v.x;
        vt[row][q * 4 + 1] = v.y;
        vt[row][q * 4 + 2] = v.z;
        vt[row][q * 4 + 3] = v.w;
    }
    for (int i = tid; i < 5 * NTT; i += P2T) ((float*)ls)[i] = 0.f;
    if (tid < PBLK)
        lcnts[tid] = __builtin_nontemporal_load(
            counts + ((size_t)g * TILES + t) * PBLK + tid);
    if (tid >= P2T - HH) {
        int h = tid - (P2T - HH);
        float a = 0.f, c = 0.f;
        for (int k = 0; k < HH; ++k) {
            float w = post_w[k * HH + h];
            a = fmaf(lin_w[k], w, a);
            c = fmaf(lin_b[k], w, c);
        }
        lpw[h] = a; lpb[h] = c;
    } else if (tid >= P2T - HH - BB) {
        int b = tid - (P2T - HH - BB);
        float l0 = mix_b[0], l1 = mix_b[1];
        for (int h = 0; h < HH; ++h) {
            float cv = ctx[b * HH + h];
            l0 = fmaf(cv, mix_w[h * GG + 0], l0);
            l1 = fmaf(cv, mix_w[h * GG + 1], l1);
        }
        float m = fmaxf(l0, l1);
        float e0 = __expf(l0 - m), e1 = __expf(l1 - m);
        lwt[b] = ((g == 0) ? e0 : e1) / (e0 + e1);
    }
    __syncthreads();

    int wv = tid >> 6, ln = tid & 63;
    const unsigned long long* bbase =
        bins + ((size_t)g * TILES + t) * PBLK * CAP;

    // main replay: 16 waves, 8 bins each (cnt ~40 -> one 64-lane pass/bin)
    for (int bI = wv; bI < PBLK; bI += P2T / 64) {
        int cnt = lcnts[bI];
        const unsigned long long* rp = bbase + (size_t)bI * CAP;
        for (int i = ln; i < cnt; i += 64) {
            unsigned long long rec = __builtin_nontemporal_load(rp + i);
            replay_rec(rec, n0, ncnt, g, guh, vt, ls, false);
        }
    }
    // spill replay (statistically ~0 records; exactness guaranteed)
    for (int bI = wv; bI < PBLK; bI += P2T / 64) {
        int sc = scnt[g * PBLK + bI];
        const unsigned long long* rp = spill + ((size_t)g * PBLK + bI) * EPB;
        for (int i = ln; i < sc; i += 64) {
            unsigned long long rec = rp[i];
            replay_rec(rec, n0, ncnt, g, guh, vt, ls, true);
        }
    }
    __syncthreads();

    // fused relu + partial-mean: (b, sub) wave-groups, h = lane
    int b   = (tid >> 6) & 3;
    int sub = tid >> 8;                  // 0..3
    int h   = tid & 63;
    float pwh = lpw[h], pbh = lpb[h], bias = post_b[h];
    float acc = 0.f;
    int i0 = sub * (NTT / 4);
    int i1 = min(i0 + (NTT / 4), ncnt);
    for (int i = i0; i < i1; ++i) {
        float x = fmaf(ls[1 + b][i], pwh, fmaf(ls[0][i], pbh, bias));
        acc += fmaxf(x, 0.f);
    }
    red[sub][b * HH + h] = acc;
    __syncthreads();
    if (tid < BB * HH) {
        float s = red[0][tid] + red[1][tid] + red[2][tid] + red[3][tid];
        int bb = tid >> 6;
        atomicAdd(&out[tid], s * lwt[bb] * (1.0f / NN));
    }
}

// ---------------------------------------------------------------------------
extern "C" void kernel_launch(void* const* d_in, const int* in_sizes, int n_in,
                              void* d_out, int out_size, void* d_ws, size_t ws_size,
                              hipStream_t stream) {
    const float* pert_mask = (const float*)d_in[0];
    const float* ctx       = (const float*)d_in[1];
    const int*   esrc      = (const int*)d_in[2];
    const int*   edst      = (const int*)d_in[3];
    const float* ewgt      = (const float*)d_in[4];
    const float* gu        = (const float*)d_in[5];
    const float* gv        = (const float*)d_in[6];
    const float* lin_w     = (const float*)d_in[7];
    const float* lin_b     = (const float*)d_in[8];
    const float* post_w    = (const float*)d_in[9];
    const float* post_b    = (const float*)d_in[10];
    const float* mix_w     = (const float*)d_in[11];
    const float* mix_b     = (const float*)d_in[12];
    float* out = (float*)d_out;

    // workspace layout (float units; 8B-aligned regions for u64 records)
    float* ws = (float*)d_ws;
    uint4* guh = (uint4*)ws;                            // 100,000 uint4 -> 400,000 f
    unsigned long long* bins = (unsigned long long*)(ws + 400000);
                                        // G*T*PBLK*CAP = 1,605,632 u64 -> 3,211,264 f
    int* counts = (int*)(ws + 3611264);                 // 25,088 int
    int* scnt   = (int*)(ws + 3636352);                 // 256 int
    unsigned long long* spill = (unsigned long long*)(ws + 3636608);
                                        // G*PBLK*EPB = 1,000,192 u64

    prep_bin_kernel<<<K1B, 256, 0, stream>>>(
        pert_mask, gu, esrc, edst, ewgt, guh, bins, counts, spill, scnt, out);

    dim3 tg(TILES, GG);
    tile_node_kernel<<<tg, P2T, 0, stream>>>(
        guh, bins, counts, spill, scnt, gv, ctx, lin_w, lin_b, post_w,
        post_b, mix_w, mix_b, out);
}

// Round 21
// 49.755 us; speedup vs baseline: 1.0507x; 1.0507x over previous
//
#include <hip/hip_runtime.h>

// Problem constants (fixed by the reference)
#define BB 4
#define NN 50000
#define GG 2
#define EE 500000
#define HH 64
#define RR 16

#define CVT (GG * NN)                    // fp8 u-table rows
#define K1B 256                          // K1 blocks total (2 graphs x 128)
#define ROWS_PB ((CVT + K1B - 1) / K1B)  // 391 table rows per K1 block

// Binning geometry (r18 measured optimum: 50.2 us)
#define NTT   512                        // nodes per dst-tile
#define TILES 98                         // ceil(NN / NTT)
#define PBLK  128                        // K1 blocks per graph
#define EPB   ((EE + PBLK - 1) / PBLK)   // 3907 edges per K1 block
#define CAP   64                         // records per (block,tile); mean 40, +3.8 sigma

typedef float f32x2 __attribute__((ext_vector_type(2)));

// ---------------------------------------------------------------------------
// fp8 helpers (OCP e4m3, hw convert on gfx950)
// ---------------------------------------------------------------------------
__device__ inline unsigned int pack4_fp8(float f0, float f1, float f2, float f3) {
    int w = 0;
    w = __builtin_amdgcn_cvt_pk_fp8_f32(f0, f1, w, false);  // bytes 0,1
    w = __builtin_amdgcn_cvt_pk_fp8_f32(f2, f3, w, true);   // bytes 2,3
    return (unsigned int)w;
}

// ---------------------------------------------------------------------------
// K1: u-table fp8 conversion (mask folded into LSBs of bytes 0..3) + edge
// binning of RAW records {src | dst<<16, ewgt_f32} by dst-tile. Direct
// cached stores (L2 write-combines them; LDS-staging measured -2us, NT
// stores measured -11us). Per-block spill region sized EPB -> unconditional
// exactness. Block 0 zeroes `out`.
// ---------------------------------------------------------------------------
__global__ __launch_bounds__(256) void prep_bin_kernel(
    const float* __restrict__ pert_mask, const float* __restrict__ gu,
    const int* __restrict__ esrc, const int* __restrict__ edst,
    const float* __restrict__ ewgt,
    uint4* __restrict__ guh, unsigned long long* __restrict__ bins,
    int* __restrict__ counts, unsigned long long* __restrict__ spill,
    int* __restrict__ scnt, float* __restrict__ out)
{
    int g   = blockIdx.x & 1;
    int blk = blockIdx.x >> 1;
    int tid = threadIdx.x;
    __shared__ int lcnt[TILES];
    __shared__ int lspill;
    if (tid < TILES) lcnt[tid] = 0;
    if (tid == 0) lspill = 0;
    if (blockIdx.x == 0 && tid < BB * HH) out[tid] = 0.f;
    __syncthreads();

    // --- u-table conversion slice (independent of edge slice) ---
    int r0 = blockIdx.x * ROWS_PB;
    int r1 = min(r0 + ROWS_PB, CVT);
    for (int r = r0 + tid; r < r1; r += 256) {
        int n = (r >= NN) ? (r - NN) : r;
        const float4* us = (const float4*)(gu + (size_t)r * RR);
        float4 a0 = us[0], a1 = us[1], a2 = us[2], a3 = us[3];
        uint4 ur;
        ur.x = pack4_fp8(a0.x, a0.y, a0.z, a0.w);
        ur.y = pack4_fp8(a1.x, a1.y, a1.z, a1.w);
        ur.z = pack4_fp8(a2.x, a2.y, a2.z, a2.w);
        ur.w = pack4_fp8(a3.x, a3.y, a3.z, a3.w);
        unsigned int mbits =
            ((pert_mask[0*NN + n] != 0.f) ? 0x1u        : 0u) |
            ((pert_mask[1*NN + n] != 0.f) ? 0x100u      : 0u) |
            ((pert_mask[2*NN + n] != 0.f) ? 0x10000u    : 0u) |
            ((pert_mask[3*NN + n] != 0.f) ? 0x1000000u  : 0u);
        ur.x = (ur.x & 0xFEFEFEFEu) | mbits;
        guh[r] = ur;
    }

    // --- edge binning (raw records; no gate math here) ---
    int base   = blk * EPB;
    int nE     = min(EPB, EE - base);
    size_t gb  = (size_t)g * EE + base;
    for (int it = tid; it < nE; it += 256) {
        int   s  = __builtin_nontemporal_load(esrc + gb + it);
        int   d  = __builtin_nontemporal_load(edst + gb + it);
        float w0 = __builtin_nontemporal_load(ewgt + gb + it);
        unsigned long long rec =
            (unsigned long long)((unsigned)s | ((unsigned)d << 16)) |
            ((unsigned long long)__float_as_uint(w0) << 32);
        int tt  = d >> 9;               // dst tile
        int pos = atomicAdd(&lcnt[tt], 1);
        if (pos < CAP) {
            bins[(((size_t)g * TILES + tt) * PBLK + blk) * CAP + pos] = rec;
        } else {
            int sp = atomicAdd(&lspill, 1);     // sp < nE <= EPB always
            spill[((size_t)g * PBLK + blk) * EPB + sp] = rec;
        }
    }
    __syncthreads();
    if (tid < TILES)
        counts[((size_t)g * TILES + tid) * PBLK + blk] = min(lcnt[tid], CAP);
    if (tid == 0) scnt[g * PBLK + blk] = lspill;
}

// ---------------------------------------------------------------------------
// K2: per (tile,g) block. v-tile loaded COALESCED from f32 gate_v into padded
// LDS [NTT][17]. Replay records: u-gather (L2) + LDS-v dot + sigmoid,
// accumulate planes, then fused ReLU-mean + out atomics.
// ---------------------------------------------------------------------------
#define P2T 1024

__device__ inline void replay_rec(
    unsigned long long rec, int n0, int ncnt, int g,
    const uint4* __restrict__ guh, float (*vt)[RR + 1], float (*ls)[NTT],
    bool check_range)
{
    unsigned int key = (unsigned int)rec;
    int d = (int)(key >> 16);
    int dl = d - n0;
    if (check_range && ((unsigned)dl >= (unsigned)ncnt)) return;
    int s = key & 0xFFFFu;
    float w0 = __uint_as_float((unsigned int)(rec >> 32));
    uint4 u = guh[(size_t)g * NN + s];      // 16B gather, L2-resident
    const unsigned int* pu = &u.x;
    float dot = 0.f;
#pragma unroll
    for (int q = 0; q < 4; ++q) {
        f32x2 lo = __builtin_amdgcn_cvt_pk_f32_fp8((int)pu[q], false);
        f32x2 hi = __builtin_amdgcn_cvt_pk_f32_fp8((int)pu[q], true);
        dot = fmaf(lo.x, vt[dl][q * 4 + 0], dot);
        dot = fmaf(lo.y, vt[dl][q * 4 + 1], dot);
        dot = fmaf(hi.x, vt[dl][q * 4 + 2], dot);
        dot = fmaf(hi.y, vt[dl][q * 4 + 3], dot);
    }
    float w = w0 / (1.f + __expf(-dot));
    unsigned int mb = (u.x & 1u) | ((u.x >> 7) & 2u) |
                      ((u.x >> 14) & 4u) | ((u.x >> 21) & 8u);
    atomicAdd(&ls[0][dl], w);
    if (mb & 1u) atomicAdd(&ls[1][dl], w);
    if (mb & 2u) atomicAdd(&ls[2][dl], w);
    if (mb & 4u) atomicAdd(&ls[3][dl], w);
    if (mb & 8u) atomicAdd(&ls[4][dl], w);
}

__global__ __launch_bounds__(P2T) void tile_node_kernel(
    const uint4* __restrict__ guh, const unsigned long long* __restrict__ bins,
    const int* __restrict__ counts, const unsigned long long* __restrict__ spill,
    const int* __restrict__ scnt, const float* __restrict__ gv,
    const float* __restrict__ ctx, const float* __restrict__ lin_w,
    const float* __restrict__ lin_b, const float* __restrict__ post_w,
    const float* __restrict__ post_b, const float* __restrict__ mix_w,
    const float* __restrict__ mix_b, float* __restrict__ out)
{
    int t = blockIdx.x;      // tile
    int g = blockIdx.y;      // graph
    int n0 = t * NTT;
    int ncnt = min(NTT, NN - n0);
    __shared__ float vt[NTT][RR + 1];    // 34.8 KB, padded rows
    __shared__ float ls[5][NTT];         // 10 KB
    __shared__ int   lcnts[PBLK];        // 512 B
    __shared__ float red[4][BB * HH];    // 4 KB
    __shared__ float lpw[HH], lpb[HH], lwt[BB];
    int tid = threadIdx.x;

    // v-tile: coalesced float4 reads, scalar LDS stores into padded rows
    for (int i = tid; i < ncnt * 4; i += P2T) {
        int row = i >> 2, q = i & 3;
        float4 v = ((const float4*)(gv + ((size_t)g * NN + n0 + row) * RR))[q];
        vt[row][q * 4 + 0] = v.x;
        vt[row][q * 4 + 1] = v.y;
        vt[row][q * 4 + 2] = v.z;
        vt[row][q * 4 + 3] = v.w;
    }
    for (int i = tid; i < 5 * NTT; i += P2T) ((float*)ls)[i] = 0.f;
    if (tid < PBLK)
        lcnts[tid] = __builtin_nontemporal_load(
            counts + ((size_t)g * TILES + t) * PBLK + tid);
    if (tid >= P2T - HH) {
        int h = tid - (P2T - HH);
        float a = 0.f, c = 0.f;
        for (int k = 0; k < HH; ++k) {
            float w = post_w[k * HH + h];
            a = fmaf(lin_w[k], w, a);
            c = fmaf(lin_b[k], w, c);
        }
        lpw[h] = a; lpb[h] = c;
    } else if (tid >= P2T - HH - BB) {
        int b = tid - (P2T - HH - BB);
        float l0 = mix_b[0], l1 = mix_b[1];
        for (int h = 0; h < HH; ++h) {
            float cv = ctx[b * HH + h];
            l0 = fmaf(cv, mix_w[h * GG + 0], l0);
            l1 = fmaf(cv, mix_w[h * GG + 1], l1);
        }
        float m = fmaxf(l0, l1);
        float e0 = __expf(l0 - m), e1 = __expf(l1 - m);
        lwt[b] = ((g == 0) ? e0 : e1) / (e0 + e1);
    }
    __syncthreads();

    int wv = tid >> 6, ln = tid & 63;
    const unsigned long long* bbase =
        bins + ((size_t)g * TILES + t) * PBLK * CAP;

    // main replay: 16 waves, 8 bins each (cnt ~40 -> one 64-lane pass/bin)
    for (int bI = wv; bI < PBLK; bI += P2T / 64) {
        int cnt = lcnts[bI];
        const unsigned long long* rp = bbase + (size_t)bI * CAP;
        for (int i = ln; i < cnt; i += 64) {
            unsigned long long rec = __builtin_nontemporal_load(rp + i);
            replay_rec(rec, n0, ncnt, g, guh, vt, ls, false);
        }
    }
    // spill replay (statistically ~0 records; exactness guaranteed)
    for (int bI = wv; bI < PBLK; bI += P2T / 64) {
        int sc = scnt[g * PBLK + bI];
        const unsigned long long* rp = spill + ((size_t)g * PBLK + bI) * EPB;
        for (int i = ln; i < sc; i += 64) {
            unsigned long long rec = rp[i];
            replay_rec(rec, n0, ncnt, g, guh, vt, ls, true);
        }
    }
    __syncthreads();

    // fused relu + partial-mean: (b, sub) wave-groups, h = lane
    int b   = (tid >> 6) & 3;
    int sub = tid >> 8;                  // 0..3
    int h   = tid & 63;
    float pwh = lpw[h], pbh = lpb[h], bias = post_b[h];
    float acc = 0.f;
    int i0 = sub * (NTT / 4);
    int i1 = min(i0 + (NTT / 4), ncnt);
    for (int i = i0; i < i1; ++i) {
        float x = fmaf(ls[1 + b][i], pwh, fmaf(ls[0][i], pbh, bias));
        acc += fmaxf(x, 0.f);
    }
    red[sub][b * HH + h] = acc;
    __syncthreads();
    if (tid < BB * HH) {
        float s = red[0][tid] + red[1][tid] + red[2][tid] + red[3][tid];
        int bb = tid >> 6;
        atomicAdd(&out[tid], s * lwt[bb] * (1.0f / NN));
    }
}

// ---------------------------------------------------------------------------
extern "C" void kernel_launch(void* const* d_in, const int* in_sizes, int n_in,
                              void* d_out, int out_size, void* d_ws, size_t ws_size,
                              hipStream_t stream) {
    const float* pert_mask = (const float*)d_in[0];
    const float* ctx       = (const float*)d_in[1];
    const int*   esrc      = (const int*)d_in[2];
    const int*   edst      = (const int*)d_in[3];
    const float* ewgt      = (const float*)d_in[4];
    const float* gu        = (const float*)d_in[5];
    const float* gv        = (const float*)d_in[6];
    const float* lin_w     = (const float*)d_in[7];
    const float* lin_b     = (const float*)d_in[8];
    const float* post_w    = (const float*)d_in[9];
    const float* post_b    = (const float*)d_in[10];
    const float* mix_w     = (const float*)d_in[11];
    const float* mix_b     = (const float*)d_in[12];
    float* out = (float*)d_out;

    // workspace layout (float units; 8B-aligned regions for u64 records)
    float* ws = (float*)d_ws;
    uint4* guh = (uint4*)ws;                            // 100,000 uint4 -> 400,000 f
    unsigned long long* bins = (unsigned long long*)(ws + 400000);
                                        // G*T*PBLK*CAP = 1,605,632 u64 -> 3,211,264 f
    int* counts = (int*)(ws + 3611264);                 // 25,088 int
    int* scnt   = (int*)(ws + 3636352);                 // 256 int
    unsigned long long* spill = (unsigned long long*)(ws + 3636608);
                                        // G*PBLK*EPB = 1,000,192 u64

    prep_bin_kernel<<<K1B, 256, 0, stream>>>(
        pert_mask, gu, esrc, edst, ewgt, guh, bins, counts, spill, scnt, out);

    dim3 tg(TILES, GG);
    tile_node_kernel<<<tg, P2T, 0, stream>>>(
        guh, bins, counts, spill, scnt, gv, ctx, lin_w, lin_b, post_w,
        post_b, mix_w, mix_b, out);
}